// Round 10
// baseline (264.358 us; speedup 1.0000x reference)
//
#include <hip/hip_runtime.h>
#include <hip/hip_bf16.h>
#include <hip/hip_fp16.h>
#include <math.h>

#define S_LEN   4096
#define B_SZ    32
#define D_DIM   64
#define L_LNK   13
#define NW_R    13
#define HF_W    128
#define HV_W    128
#define VOCAB_N 512
#define NC_N    2

#define NT      1024           // threads per block
#define STRIDE  1024           // chord rows per thread-stride
#define NROW    4              // rows per thread
#define MIRROR  512            // mirrored rows (max LDS link offset = 512)
#define BUFN    (S_LEN + MIRROR)
#define NBLOCKS (16 * B_SZ)    // 512 = exactly 2 blocks/CU on 256 CUs

// Z is iterated in a scaled domain Z' = Z/16 (power-of-2, exact) so fp16
// accumulation intermediates stay inside fp16 range (ref |Z| ~ 44k).
#define ZSCALE     16.0f
#define ZSCALE_INV 0.0625f

typedef float vf4 __attribute__((ext_vector_type(4)));

__device__ __forceinline__ float gelu_erf(float x) {
    return 0.5f * x * (1.0f + erff(x * 0.70710678118654752440f));
}

// fp16x4 pack (order: lo16(x), hi16(x), lo16(y), hi16(y))
__device__ __forceinline__ uint2 pack4h(vf4 v) {
    __half2 a = __float22half2_rn(float2{v.x, v.y});
    __half2 b = __float22half2_rn(float2{v.z, v.w});
    uint2 r;
    r.x = *reinterpret_cast<unsigned int*>(&a);
    r.y = *reinterpret_cast<unsigned int*>(&b);
    return r;
}

// --- v_pk_fma_f16 / v_pk_mul_f16 / v_pk_add_f16 (VOP3P, full rate) --------
__device__ __forceinline__ unsigned pk_fma_lo(unsigned c, unsigned z, unsigned a) {
    unsigned d;
    asm("v_pk_fma_f16 %0, %1, %2, %3 op_sel:[0,0,0] op_sel_hi:[0,1,1]"
        : "=v"(d) : "v"(c), "v"(z), "v"(a));
    return d;
}
__device__ __forceinline__ unsigned pk_fma_hi(unsigned c, unsigned z, unsigned a) {
    unsigned d;
    asm("v_pk_fma_f16 %0, %1, %2, %3 op_sel:[1,0,0] op_sel_hi:[1,1,1]"
        : "=v"(d) : "v"(c), "v"(z), "v"(a));
    return d;
}
__device__ __forceinline__ unsigned pk_mul_lo(unsigned c, unsigned z) {
    unsigned d;
    asm("v_pk_mul_f16 %0, %1, %2 op_sel:[0,0] op_sel_hi:[0,1]"
        : "=v"(d) : "v"(c), "v"(z));
    return d;
}
__device__ __forceinline__ unsigned pk_add(unsigned a, unsigned b) {
    unsigned d;
    asm("v_pk_add_f16 %0, %1, %2" : "=v"(d) : "v"(a), "v"(b));
    return d;
}
__device__ __forceinline__ void pk2_lo(uint2& a, unsigned c, uint2 z) {
    a.x = pk_fma_lo(c, z.x, a.x);
    a.y = pk_fma_lo(c, z.y, a.y);
}
__device__ __forceinline__ void pk2_hi(uint2& a, unsigned c, uint2 z) {
    a.x = pk_fma_hi(c, z.x, a.x);
    a.y = pk_fma_hi(c, z.y, a.y);
}

// ---------------------------------------------------------------------------
// Fused kernel, PLAIN launch. Grid dim3(16,32) = 512 blocks x 1024 thr =
// exactly 2 blocks/CU (LDS 74KB, VGPR<=64 via launch_bounds) -> all blocks
// structurally co-resident -> manual spin barrier is deadlock-free. A
// bail-out cap (~0.2s) guarantees termination even if that assumption broke.
//
// Phase 0 (tables): block (ds,b) owns token b*16+ds; 8 groups x 128 thr
// evaluate the 14 table units (13 FNet + 1 VNet) in 2 passes into the
// workspace (scratch overlays the Zs slab).
// Barrier: release-fence + agent atomicAdd on bar (memset to 0 by host each
// launch); spin until 512 arrivals; acquire-fence.
// Phase 1 (logits + chord): byte-identical to the verified R8 kernel.
// ---------------------------------------------------------------------------
__global__ __launch_bounds__(NT, 8)
void fused_kernel(const int* __restrict__ tok,
                  const float* __restrict__ emb,
                  const float* __restrict__ fW1, const float* __restrict__ fb1,
                  const float* __restrict__ fW2, const float* __restrict__ fb2,
                  const float* __restrict__ vW1, const float* __restrict__ vb1,
                  const float* __restrict__ vW2, const float* __restrict__ vb2,
                  const float* __restrict__ finW, const float* __restrict__ finb,
                  __half* __restrict__ F_table, float* __restrict__ V_table,
                  unsigned* __restrict__ bar,
                  float* __restrict__ out, float* __restrict__ Zout) {
    __shared__ uint2 Zs[2][BUFN];
    __shared__ float slog[16][2];
    const int b  = blockIdx.y;
    const int ds = blockIdx.x;
    const int t  = threadIdx.x;

    // ===================== Phase 0: tables for token tkn =====================
    {
        const int tkn = b * 16 + ds;               // 0..511
        float* sf = (float*)&Zs[0][0];             // overlay scratch on Zs
        float* s_emb = sf;                         // [64]
        float (*s_red)[2][16] = (float (*)[2][16])(sf + 64);   // [8][2][16]
        float* s_HV = sf + 64 + 256;               // [128]
        const int g = t >> 7;                      // group 0..7 (128 thr each)
        const int u = t & 127;

        if (t < D_DIM) s_emb[t] = emb[tkn * D_DIM + t];
        __syncthreads();

        #pragma unroll
        for (int p = 0; p < 2; ++p) {
            const int unit = g + 8 * p;            // 0..12 FNet k, 13 VNet
            float pr[L_LNK];
            if (unit < L_LNK) {
                const int k = unit;
                float acc = fb1[k * HF_W + u];
                const float* w = fW1 + (size_t)k * D_DIM * HF_W + u;
                #pragma unroll 8
                for (int d = 0; d < D_DIM; ++d) acc += s_emb[d] * w[d * HF_W];
                const float hval = gelu_erf(acc);
                const float* w2 = fW2 + ((size_t)k * HF_W + u) * L_LNK;
                #pragma unroll
                for (int l = 0; l < L_LNK; ++l) pr[l] = hval * w2[l];
                #pragma unroll
                for (int o = 1; o < 64; o <<= 1) {
                    #pragma unroll
                    for (int l = 0; l < L_LNK; ++l) pr[l] += __shfl_xor(pr[l], o, 64);
                }
                if ((u & 63) == 0) {
                    const int wv = u >> 6;
                    #pragma unroll
                    for (int l = 0; l < L_LNK; ++l) s_red[g][wv][l] = pr[l];
                }
            } else if (unit == 13) {
                float acc = vb1[u];
                const float* w = vW1 + u;
                #pragma unroll 8
                for (int d = 0; d < D_DIM; ++d) acc += s_emb[d] * w[d * HV_W];
                s_HV[u] = gelu_erf(acc);
            }
            __syncthreads();
            if (unit < L_LNK) {
                if (u < L_LNK) {
                    float o = fb2[unit * L_LNK + u]
                            + s_red[g][0][u] + s_red[g][1][u];
                    F_table[((size_t)(unit * VOCAB_N + tkn)) * 16 + u] =
                        __float2half_rn(o);
                }
            } else if (unit == 13 && u < D_DIM) {
                float o = vb2[u];
                const float* w2 = vW2 + u;
                #pragma unroll 8
                for (int h = 0; h < HV_W; ++h) o += s_HV[h] * w2[h * D_DIM];
                V_table[tkn * D_DIM + u] = o;
            }
            __syncthreads();   // protect s_red / s_HV reuse in pass 2 (WAR)
        }
    }

    // =================== software grid barrier (512 blocks) =================
    // All blocks are co-resident by construction; bail-out cap guarantees
    // termination regardless. bar is memset to 0 by the host each launch.
    __syncthreads();           // block's table writes ordered before release
    if (t == 0) {
        __threadfence();       // agent-scope release of this block's writes
        __hip_atomic_fetch_add(bar, 1u, __ATOMIC_RELEASE, __HIP_MEMORY_SCOPE_AGENT);
        unsigned spins = 0;
        while (__hip_atomic_load(bar, __ATOMIC_ACQUIRE, __HIP_MEMORY_SCOPE_AGENT)
               < (unsigned)NBLOCKS) {
            __builtin_amdgcn_s_sleep(2);
            if (++spins > (1u << 22)) break;   // ~0.2s cap: never hang
        }
        __threadfence();       // acquire: invalidate stale cached table lines
    }
    __syncthreads();

    // ================= Phase 1: logits + chord (R8, verified) ===============
    const vf4* V4 = (const vf4*)V_table;

    unsigned tokf[NROW];
    uint2 Vp[NROW], zp[NROW];
    #pragma unroll
    for (int j = 0; j < NROW; ++j) {
        const int r = t + STRIDE * j;
        const int tk = tok[b * S_LEN + r];
        tokf[j] = (unsigned)tk * 32u;
        vf4 v = V4[tk * 16 + ds];
        v.x *= ZSCALE_INV; v.y *= ZSCALE_INV;
        v.z *= ZSCALE_INV; v.w *= ZSCALE_INV;
        uint2 p = pack4h(v);
        Vp[j] = p; zp[j] = p;
        Zs[0][r] = p;
    }
    if (t < MIRROR) Zs[0][S_LEN + t] = zp[0];   // waves 0..7: uniform branch

    // --- fused logits: contiguous finW chunk rows [ds*256,(ds+1)*256) ---
    float l0 = 0.0f, l1 = 0.0f;
    {
        const int rb = ds << 8;
        const float4* W0 = (const float4*)finW;
        const float4* W1 = (const float4*)(finW + (size_t)S_LEN * D_DIM);
        const float4* Vt = (const float4*)V_table;
        #pragma unroll
        for (int q = 0; q < 4; ++q) {
            const int i = t + NT * q;        // 0..4095
            const int r = rb + (i >> 4);     // chunk row
            const int c4 = i & 15;           // float4 column
            const int tk = tok[b * S_LEN + r];
            float4 v  = Vt[tk * 16 + c4];
            float4 w0 = W0[(size_t)r * 16 + c4];
            float4 w1 = W1[(size_t)r * 16 + c4];
            l0 += v.x * w0.x + v.y * w0.y + v.z * w0.z + v.w * w0.w;
            l1 += v.x * w1.x + v.y * w1.y + v.z * w1.z + v.w * w1.w;
        }
    }
    #pragma unroll
    for (int o = 32; o > 0; o >>= 1) {
        l0 += __shfl_down(l0, o, 64);
        l1 += __shfl_down(l1, o, 64);
    }
    if ((t & 63) == 0) { slog[t >> 6][0] = l0; slog[t >> 6][1] = l1; }
    __syncthreads();
    if (t == 0) {
        float s0 = 0.0f, s1 = 0.0f;
        #pragma unroll
        for (int i = 0; i < 16; ++i) { s0 += slog[i][0]; s1 += slog[i][1]; }
        if (ds == 0) { s0 += finb[0]; s1 += finb[1]; }
        atomicAdd(&out[b * NC_N + 0], s0);
        atomicAdd(&out[b * NC_N + 1], s1);
    }

    int cur = 0;
    uint2 acc[NROW];
    #pragma unroll 1
    for (int k = 0; k < NW_R; ++k) {
        const char* Fk = (const char*)F_table + (size_t)k * (VOCAB_N * 32);
        const uint2* Zc = Zs[cur];
        uint2* Zn = Zs[cur ^ 1];
        const bool wr = (k < NW_R - 1);
        #pragma unroll
        for (int j = 0; j < NROW; ++j) {
            const int r = t + STRIDE * j;
            const char* Fr = Fk + tokf[j];
            uint4 u0 = *(const uint4*)Fr;            // coeffs c0..c7
            uint4 u1 = *(const uint4*)(Fr + 16);     // c8..c12 (+pad, unused)
            // half-index -> offset: c0:0 c1:1 c2:2 c3:4 c4:8 c5:16 c6:32
            //                       c7:64 c8:128 c9:256 c10:512 c11:1024 c12:2048
            // word/half map: u0.x=(c0,c1) u0.y=(c2,c3) u0.z=(c4,c5) u0.w=(c6,c7)
            //                u1.x=(c8,c9) u1.y=(c10,c11) u1.z=(c12,pad)
            uint2 a, a2;
            a.x = pk_fma_lo(u0.x, zp[j].x, Vp[j].x); // c0 (off 0) + residual
            a.y = pk_fma_lo(u0.x, zp[j].y, Vp[j].y);
            {
                uint2 z32 = Zc[r + 32];
                a2.x = pk_mul_lo(u0.w, z32.x);       // c6 seeds chain B
                a2.y = pk_mul_lo(u0.w, z32.y);
            }
            pk2_hi(a,  u0.x, Zc[r + 1]);             // c1
            pk2_lo(a,  u0.y, Zc[r + 2]);             // c2
            pk2_hi(a,  u0.y, Zc[r + 4]);             // c3
            pk2_lo(a,  u0.z, Zc[r + 8]);             // c4
            pk2_hi(a,  u0.z, Zc[r + 16]);            // c5
            pk2_hi(a2, u0.w, Zc[r + 64]);            // c7
            pk2_lo(a2, u1.x, Zc[r + 128]);           // c8
            pk2_hi(a2, u1.x, Zc[r + 256]);           // c9
            pk2_lo(a2, u1.y, Zc[r + 512]);           // c10, off 512 (LDS)
            pk2_hi(a2, u1.y, zp[(j + 1) & 3]);       // c11, off 1024 (reg)
            pk2_lo(a2, u1.z, zp[(j + 2) & 3]);       // c12, off 2048 (reg)
            uint2 s;
            s.x = pk_add(a.x, a2.x);
            s.y = pk_add(a.y, a2.y);
            acc[j] = s;
            if (wr) {                                // early write: overlaps
                Zn[r] = s;                           // later rows' reads/FMAs
                if (j == 0 && t < MIRROR) Zn[S_LEN + t] = s;
            }
        }
        if (wr) {
            #pragma unroll
            for (int j = 0; j < NROW; ++j) zp[j] = acc[j];  // after reg-link uses
        }
        __syncthreads();   // single barrier/round (double buffer -> no WAR)
        cur ^= 1;
    }

    #pragma unroll
    for (int j = 0; j < NROW; ++j) {
        const int r = t + STRIDE * j;
        __half2 h0 = *reinterpret_cast<__half2*>(&acc[j].x);
        __half2 h1 = *reinterpret_cast<__half2*>(&acc[j].y);
        float2 f0 = __half22float2(h0);
        float2 f1 = __half22float2(h1);
        vf4 o;
        o.x = f0.x * ZSCALE; o.y = f0.y * ZSCALE;
        o.z = f1.x * ZSCALE; o.w = f1.y * ZSCALE;
        *(vf4*)(Zout + (((size_t)b * S_LEN + r) << 6) + ds * 4) = o;
    }
}

extern "C" void kernel_launch(void* const* d_in, const int* in_sizes, int n_in,
                              void* d_out, int out_size, void* d_ws, size_t ws_size,
                              hipStream_t stream) {
    const int*   tok  = (const int*)d_in[0];
    const float* emb  = (const float*)d_in[1];
    const float* fW1  = (const float*)d_in[2];
    const float* fb1  = (const float*)d_in[3];
    const float* fW2  = (const float*)d_in[4];
    const float* fb2  = (const float*)d_in[5];
    const float* vW1  = (const float*)d_in[6];
    const float* vb1  = (const float*)d_in[7];
    const float* vW2  = (const float*)d_in[8];
    const float* vb2  = (const float*)d_in[9];
    const float* finW = (const float*)d_in[10];
    const float* finb = (const float*)d_in[11];

    float* out = (float*)d_out;          // (B, NC) = 64 floats
    float* Z   = out + B_SZ * NC_N;      // (B, S, D) fp32

    float*   V_table = (float*)d_ws;                         // 512*64 f32
    __half*  F_table = (__half*)(V_table + VOCAB_N * D_DIM); // 13*512*16 f16
    unsigned* bar    = (unsigned*)((char*)F_table
                                   + (size_t)NW_R * VOCAB_N * 16 * sizeof(__half));

    // d_ws may be (re)poisoned between iterations -> zero the barrier word
    // each launch. out[] is zeroed by the harness; logits accumulate via
    // atomicAdd in the fused kernel.
    hipMemsetAsync(bar, 0, 8, stream);
    fused_kernel<<<dim3(16, B_SZ), NT, 0, stream>>>(
        tok, emb, fW1, fb1, fW2, fb2, vW1, vb1, vW2, vb2, finW, finb,
        F_table, V_table, bar, out, Z);
}

// Round 11
// 184.849 us; speedup vs baseline: 1.4301x; 1.4301x over previous
//
#include <hip/hip_runtime.h>
#include <hip/hip_bf16.h>
#include <hip/hip_fp16.h>
#include <math.h>

#define S_LEN   4096
#define B_SZ    32
#define D_DIM   64
#define L_LNK   13
#define NW_R    13
#define HF_W    128
#define HV_W    128
#define VOCAB_N 512
#define NC_N    2

#define NT      1024           // chord threads per block
#define STRIDE  1024           // chord rows per thread-stride
#define NROW    4              // rows per thread
#define MIRROR  512            // mirrored rows (max LDS link offset = 512)
#define BUFN    (S_LEN + MIRROR)

// Z is iterated in a scaled domain Z' = Z/16 (power-of-2, exact) so fp16
// accumulation intermediates stay inside fp16 range (ref |Z| ~ 44k).
#define ZSCALE     16.0f
#define ZSCALE_INV 0.0625f

typedef float vf4 __attribute__((ext_vector_type(4)));

__device__ __forceinline__ float gelu_erf(float x) {
    return 0.5f * x * (1.0f + erff(x * 0.70710678118654752440f));
}

// fp16x4 pack (order: lo16(x), hi16(x), lo16(y), hi16(y))
__device__ __forceinline__ uint2 pack4h(vf4 v) {
    __half2 a = __float22half2_rn(float2{v.x, v.y});
    __half2 b = __float22half2_rn(float2{v.z, v.w});
    uint2 r;
    r.x = *reinterpret_cast<unsigned int*>(&a);
    r.y = *reinterpret_cast<unsigned int*>(&b);
    return r;
}

// --- v_pk_fma_f16 / v_pk_mul_f16 / v_pk_add_f16 (VOP3P, full rate) --------
// coeff broadcast via op_sel / op_sel_hi on src0 (no splat instructions).
__device__ __forceinline__ unsigned pk_fma_lo(unsigned c, unsigned z, unsigned a) {
    unsigned d;
    asm("v_pk_fma_f16 %0, %1, %2, %3 op_sel:[0,0,0] op_sel_hi:[0,1,1]"
        : "=v"(d) : "v"(c), "v"(z), "v"(a));
    return d;
}
__device__ __forceinline__ unsigned pk_fma_hi(unsigned c, unsigned z, unsigned a) {
    unsigned d;
    asm("v_pk_fma_f16 %0, %1, %2, %3 op_sel:[1,0,0] op_sel_hi:[1,1,1]"
        : "=v"(d) : "v"(c), "v"(z), "v"(a));
    return d;
}
__device__ __forceinline__ unsigned pk_mul_lo(unsigned c, unsigned z) {
    unsigned d;
    asm("v_pk_mul_f16 %0, %1, %2 op_sel:[0,0] op_sel_hi:[0,1]"
        : "=v"(d) : "v"(c), "v"(z));
    return d;
}
__device__ __forceinline__ unsigned pk_add(unsigned a, unsigned b) {
    unsigned d;
    asm("v_pk_add_f16 %0, %1, %2" : "=v"(d) : "v"(a), "v"(b));
    return d;
}
__device__ __forceinline__ void pk2_lo(uint2& a, unsigned c, uint2 z) {
    a.x = pk_fma_lo(c, z.x, a.x);
    a.y = pk_fma_lo(c, z.y, a.y);
}
__device__ __forceinline__ void pk2_hi(uint2& a, unsigned c, uint2 z) {
    a.x = pk_fma_hi(c, z.x, a.x);
    a.y = pk_fma_hi(c, z.y, a.y);
}

// ---------------------------------------------------------------------------
// Kernel A: per-token tables (unchanged from R5). Grid: 13*512 + 512 x 128.
// ---------------------------------------------------------------------------
__global__ __launch_bounds__(128)
void tables_kernel(const float* __restrict__ emb,
                   const float* __restrict__ fW1, const float* __restrict__ fb1,
                   const float* __restrict__ fW2, const float* __restrict__ fb2,
                   const float* __restrict__ vW1, const float* __restrict__ vb1,
                   const float* __restrict__ vW2, const float* __restrict__ vb2,
                   __half* __restrict__ F_table, float* __restrict__ V_table) {
    __shared__ float s_emb[D_DIM];
    __shared__ float s_H[HF_W];
    __shared__ float s_red[2][16];
    const int blk = blockIdx.x;
    const int tid = threadIdx.x;

    if (blk < NW_R * VOCAB_N) {
        const int k = blk >> 9;
        const int t = blk & (VOCAB_N - 1);
        if (tid < D_DIM) s_emb[tid] = emb[t * D_DIM + tid];
        __syncthreads();
        float acc = fb1[k * HF_W + tid];
        const float* w = fW1 + (size_t)k * D_DIM * HF_W + tid;
        #pragma unroll 8
        for (int d = 0; d < D_DIM; ++d) acc += s_emb[d] * w[d * HF_W];
        const float hval = gelu_erf(acc);
        const float* w2 = fW2 + ((size_t)k * HF_W + tid) * L_LNK;
        float p[L_LNK];
        #pragma unroll
        for (int l = 0; l < L_LNK; ++l) p[l] = hval * w2[l];
        #pragma unroll
        for (int o = 1; o < 64; o <<= 1) {
            #pragma unroll
            for (int l = 0; l < L_LNK; ++l) p[l] += __shfl_xor(p[l], o, 64);
        }
        if ((tid & 63) == 0) {
            const int wv = tid >> 6;
            #pragma unroll
            for (int l = 0; l < L_LNK; ++l) s_red[wv][l] = p[l];
        }
        __syncthreads();
        if (tid < L_LNK) {
            float o = fb2[k * L_LNK + tid] + s_red[0][tid] + s_red[1][tid];
            F_table[((size_t)(k * VOCAB_N + t)) * 16 + tid] = __float2half_rn(o);
        }
    } else {
        const int t = blk - NW_R * VOCAB_N;
        if (tid < D_DIM) s_emb[tid] = emb[t * D_DIM + tid];
        __syncthreads();
        float acc = vb1[tid];
        const float* w = vW1 + tid;
        #pragma unroll 8
        for (int d = 0; d < D_DIM; ++d) acc += s_emb[d] * w[d * HV_W];
        s_H[tid] = gelu_erf(acc);
        __syncthreads();
        if (tid < D_DIM) {
            float o = vb2[tid];
            const float* w2 = vW2 + tid;
            #pragma unroll 8
            for (int h = 0; h < HV_W; ++h) o += s_H[h] * w2[h * D_DIM];
            V_table[t * D_DIM + tid] = o;
        }
    }
}

// ---------------------------------------------------------------------------
// Kernel C: chord sparse-multiply + fused logits (verified R8 body).
// R11 change: XCD-co-locating block swizzle. Zout rows are 256 B but each
// block writes only a 16 B sliver (its 4 dims) -> with the default ds-fastest
// dispatch, the 16 slivers of one row land on DIFFERENT XCDs (round-robin
// n%8), whose private L2s each write back partial 32 B sectors: measured
// WRITE_SIZE = 65.5 MB for a 33.6 MB output (2x amplification). 1-D grid
// with n = (ds&1)*256 + (ds>>1)*32 + b puts ALL 16 ds-blocks of batch b on
// XCD b%8 (64 blocks/XCD, balanced, all co-resident) -> slivers merge into
// full lines in L2 before writeback. Bonus: tok/F reads of a batch share L2.
// Grid: 512 x 1024.
// ---------------------------------------------------------------------------
__global__ __launch_bounds__(NT, 8)
void chord_kernel(const int* __restrict__ tok,
                  const __half* __restrict__ F_table,
                  const float* __restrict__ V_table,
                  const float* __restrict__ finW,
                  const float* __restrict__ finb,
                  float* __restrict__ out,
                  float* __restrict__ Zout) {
    __shared__ uint2 Zs[2][BUFN];
    __shared__ float slog[16][2];
    const int n  = blockIdx.x;
    const int b  = n & 31;                         // batch
    const int ds = ((n >> 5) & 7) * 2 + (n >> 8);  // dim-slice 0..15
    const int t  = threadIdx.x;
    const vf4* V4 = (const vf4*)V_table;

    // --- chord V staging (own rows t + 1024j, own 4-dim slice ds) ---
    unsigned tokf[NROW];
    uint2 Vp[NROW], zp[NROW];
    #pragma unroll
    for (int j = 0; j < NROW; ++j) {
        const int r = t + STRIDE * j;
        const int tk = tok[b * S_LEN + r];
        tokf[j] = (unsigned)tk * 32u;
        vf4 v = V4[tk * 16 + ds];
        v.x *= ZSCALE_INV; v.y *= ZSCALE_INV;
        v.z *= ZSCALE_INV; v.w *= ZSCALE_INV;
        uint2 p = pack4h(v);
        Vp[j] = p; zp[j] = p;
        Zs[0][r] = p;
    }
    if (t < MIRROR) Zs[0][S_LEN + t] = zp[0];   // waves 0..7: uniform branch

    // --- fused logits: contiguous finW chunk rows [ds*256,(ds+1)*256) ---
    float l0 = 0.0f, l1 = 0.0f;
    {
        const int rb = ds << 8;
        const float4* W0 = (const float4*)finW;
        const float4* W1 = (const float4*)(finW + (size_t)S_LEN * D_DIM);
        const float4* Vt = (const float4*)V_table;
        #pragma unroll
        for (int q = 0; q < 4; ++q) {
            const int i = t + NT * q;        // 0..4095
            const int r = rb + (i >> 4);     // chunk row
            const int c4 = i & 15;           // float4 column
            const int tk = tok[b * S_LEN + r];
            float4 v  = Vt[tk * 16 + c4];
            float4 w0 = W0[(size_t)r * 16 + c4];
            float4 w1 = W1[(size_t)r * 16 + c4];
            l0 += v.x * w0.x + v.y * w0.y + v.z * w0.z + v.w * w0.w;
            l1 += v.x * w1.x + v.y * w1.y + v.z * w1.z + v.w * w1.w;
        }
    }
    #pragma unroll
    for (int o = 32; o > 0; o >>= 1) {
        l0 += __shfl_down(l0, o, 64);
        l1 += __shfl_down(l1, o, 64);
    }
    if ((t & 63) == 0) { slog[t >> 6][0] = l0; slog[t >> 6][1] = l1; }
    __syncthreads();
    if (t == 0) {
        float s0 = 0.0f, s1 = 0.0f;
        #pragma unroll
        for (int i = 0; i < 16; ++i) { s0 += slog[i][0]; s1 += slog[i][1]; }
        if (ds == 0) { s0 += finb[0]; s1 += finb[1]; }
        atomicAdd(&out[b * NC_N + 0], s0);
        atomicAdd(&out[b * NC_N + 1], s1);
    }

    int cur = 0;
    uint2 acc[NROW];
    #pragma unroll 1
    for (int k = 0; k < NW_R; ++k) {
        const char* Fk = (const char*)F_table + (size_t)k * (VOCAB_N * 32);
        const uint2* Zc = Zs[cur];
        uint2* Zn = Zs[cur ^ 1];
        const bool wr = (k < NW_R - 1);
        #pragma unroll
        for (int j = 0; j < NROW; ++j) {
            const int r = t + STRIDE * j;
            const char* Fr = Fk + tokf[j];
            uint4 u0 = *(const uint4*)Fr;            // coeffs c0..c7
            uint4 u1 = *(const uint4*)(Fr + 16);     // c8..c12 (+pad, unused)
            // half-index -> offset: c0:0 c1:1 c2:2 c3:4 c4:8 c5:16 c6:32
            //                       c7:64 c8:128 c9:256 c10:512 c11:1024 c12:2048
            // word/half map: u0.x=(c0,c1) u0.y=(c2,c3) u0.z=(c4,c5) u0.w=(c6,c7)
            //                u1.x=(c8,c9) u1.y=(c10,c11) u1.z=(c12,pad)
            uint2 a, a2;
            a.x = pk_fma_lo(u0.x, zp[j].x, Vp[j].x); // c0 (off 0) + residual
            a.y = pk_fma_lo(u0.x, zp[j].y, Vp[j].y);
            {
                uint2 z32 = Zc[r + 32];
                a2.x = pk_mul_lo(u0.w, z32.x);       // c6 seeds chain B
                a2.y = pk_mul_lo(u0.w, z32.y);
            }
            pk2_hi(a,  u0.x, Zc[r + 1]);             // c1
            pk2_lo(a,  u0.y, Zc[r + 2]);             // c2
            pk2_hi(a,  u0.y, Zc[r + 4]);             // c3
            pk2_lo(a,  u0.z, Zc[r + 8]);             // c4
            pk2_hi(a,  u0.z, Zc[r + 16]);            // c5
            pk2_hi(a2, u0.w, Zc[r + 64]);            // c7
            pk2_lo(a2, u1.x, Zc[r + 128]);           // c8
            pk2_hi(a2, u1.x, Zc[r + 256]);           // c9
            pk2_lo(a2, u1.y, Zc[r + 512]);           // c10, off 512 (LDS)
            pk2_hi(a2, u1.y, zp[(j + 1) & 3]);       // c11, off 1024 (reg)
            pk2_lo(a2, u1.z, zp[(j + 2) & 3]);       // c12, off 2048 (reg)
            uint2 s;
            s.x = pk_add(a.x, a2.x);
            s.y = pk_add(a.y, a2.y);
            acc[j] = s;
            if (wr) {                                // early write: overlaps
                Zn[r] = s;                           // later rows' reads/FMAs
                if (j == 0 && t < MIRROR) Zn[S_LEN + t] = s;
            }
        }
        if (wr) {
            #pragma unroll
            for (int j = 0; j < NROW; ++j) zp[j] = acc[j];  // after reg-link uses
        }
        __syncthreads();   // single barrier/round (double buffer -> no WAR)
        cur ^= 1;
    }

    #pragma unroll
    for (int j = 0; j < NROW; ++j) {
        const int r = t + STRIDE * j;
        __half2 h0 = *reinterpret_cast<__half2*>(&acc[j].x);
        __half2 h1 = *reinterpret_cast<__half2*>(&acc[j].y);
        float2 f0 = __half22float2(h0);
        float2 f1 = __half22float2(h1);
        vf4 o;
        o.x = f0.x * ZSCALE; o.y = f0.y * ZSCALE;
        o.z = f1.x * ZSCALE; o.w = f1.y * ZSCALE;
        *(vf4*)(Zout + (((size_t)b * S_LEN + r) << 6) + ds * 4) = o;
    }
}

extern "C" void kernel_launch(void* const* d_in, const int* in_sizes, int n_in,
                              void* d_out, int out_size, void* d_ws, size_t ws_size,
                              hipStream_t stream) {
    const int*   tok  = (const int*)d_in[0];
    const float* emb  = (const float*)d_in[1];
    const float* fW1  = (const float*)d_in[2];
    const float* fb1  = (const float*)d_in[3];
    const float* fW2  = (const float*)d_in[4];
    const float* fb2  = (const float*)d_in[5];
    const float* vW1  = (const float*)d_in[6];
    const float* vb1  = (const float*)d_in[7];
    const float* vW2  = (const float*)d_in[8];
    const float* vb2  = (const float*)d_in[9];
    const float* finW = (const float*)d_in[10];
    const float* finb = (const float*)d_in[11];

    float* out = (float*)d_out;          // (B, NC) = 64 floats
    float* Z   = out + B_SZ * NC_N;      // (B, S, D) fp32

    float*  V_table = (float*)d_ws;                         // 512*64 f32
    __half* F_table = (__half*)(V_table + VOCAB_N * D_DIM); // 13*512*16 f16

    // out[] is zeroed by the harness before the checked launch and between
    // timing iterations; logits accumulate via atomicAdd in chord_kernel.
    tables_kernel<<<NW_R * VOCAB_N + VOCAB_N, 128, 0, stream>>>(
        emb, fW1, fb1, fW2, fb2, vW1, vb1, vW2, vb2, F_table, V_table);
    chord_kernel<<<512, NT, 0, stream>>>(
        tok, F_table, V_table, finW, finb, out, Z);
}